// Round 7
// baseline (100.244 us; speedup 1.0000x reference)
//
#include <hip/hip_runtime.h>

#define V   1024
#define NH  16384
#define NM  16384

#define BAND_LOW_MAX    500.0f
#define BAND_MID_MAX    2000.0f
#define ENERGY_THRESHOLD 0.5f

// clang native vector type (required by __builtin_nontemporal_*)
typedef float f32x4 __attribute__((ext_vector_type(4)));

// ---------------------------------------------------------------------------
// Kernel 1: per-voice band stats + last-block gains computation.
// Grid = V blocks x 256. stats planar [5][V]: {E0*af, E1*af, E2*af, cw*af, af}.
// The LAST block to finish (device-scope atomic counter) recomputes the
// totals (fixed deterministic tree over the complete stats array) and writes
// gains[V][4] = {g_low, g_mid, g_high, noise_scale_eff}.
// Cross-XCD safety: stats re-read uses agent-scope atomic loads (per-XCD L2
// may hold stale lines written by other XCDs - G16).
// ---------------------------------------------------------------------------
__global__ __launch_bounds__(256)
void k1_stats(const float* __restrict__ harm,
              const float* __restrict__ f0_hz,
              const float* __restrict__ cw,
              const float* __restrict__ wd,
              const int*   __restrict__ is_active,
              float* __restrict__ stats /* [5][V] */,
              float* __restrict__ gains /* [V][4] */,
              unsigned int* __restrict__ counter) {
    const int v   = blockIdx.x;
    const int tid = threadIdx.x;
    const float f0 = f0_hz[v];
    const f32x4* hrow = (const f32x4*)harm + (size_t)v * 4096;

    float e0 = 0.f, e1 = 0.f, e2 = 0.f;
    #pragma unroll
    for (int k = 0; k < 16; ++k) {
        const f32x4 a = hrow[tid + k * 256];
        const int hbase = (tid + k * 256) * 4;
        #pragma unroll
        for (int j = 0; j < 4; ++j) {
            const float freq = f0 * (float)(hbase + j + 1);  // fp32 mul, matches jnp
            if (freq < BAND_LOW_MAX)       e0 += a[j];
            else if (freq < BAND_MID_MAX)  e1 += a[j];
            else                           e2 += a[j];
        }
    }
    for (int off = 32; off > 0; off >>= 1) {
        e0 += __shfl_down(e0, off);
        e1 += __shfl_down(e1, off);
        e2 += __shfl_down(e2, off);
    }
    __shared__ float s[3][4];
    __shared__ bool is_last;
    const int wid  = tid >> 6;
    const int lane = tid & 63;
    if (lane == 0) { s[0][wid] = e0; s[1][wid] = e1; s[2][wid] = e2; }
    __syncthreads();
    if (tid == 0) {
        const float t0 = s[0][0] + s[0][1] + s[0][2] + s[0][3];
        const float t1 = s[1][0] + s[1][1] + s[1][2] + s[1][3];
        const float t2 = s[2][0] + s[2][1] + s[2][2] + s[2][3];
        const float af = (is_active[v] != 0) ? 1.0f : 0.0f;
        stats[0 * V + v] = t0 * af;
        stats[1 * V + v] = t1 * af;
        stats[2 * V + v] = t2 * af;
        stats[3 * V + v] = cw[v] * af;
        stats[4 * V + v] = af;
        __threadfence();   // release stats before the counter bump
        const unsigned int old = __hip_atomic_fetch_add(
            counter, 1u, __ATOMIC_ACQ_REL, __HIP_MEMORY_SCOPE_AGENT);
        is_last = (old == V - 1);
    }
    __syncthreads();
    if (!is_last) return;

    // ---- last block only: totals + gains for all V voices ----------------
    // Thread t owns voices 4t .. 4t+3. Agent-scope loads (L2-coherent).
    float sv[5][4];
    #pragma unroll
    for (int p = 0; p < 5; ++p) {
        #pragma unroll
        for (int j = 0; j < 4; ++j) {
            sv[p][j] = __hip_atomic_load(&stats[p * V + 4 * tid + j],
                                         __ATOMIC_RELAXED, __HIP_MEMORY_SCOPE_AGENT);
        }
    }
    float r[5];
    #pragma unroll
    for (int p = 0; p < 5; ++p)
        r[p] = (sv[p][0] + sv[p][1]) + (sv[p][2] + sv[p][3]);
    #pragma unroll
    for (int p = 0; p < 5; ++p)
        for (int off = 32; off > 0; off >>= 1)
            r[p] += __shfl_down(r[p], off);
    __shared__ float s2[5][4];
    if (lane == 0) {
        #pragma unroll
        for (int p = 0; p < 5; ++p) s2[p][wid] = r[p];
    }
    __syncthreads();
    const float TE[3] = {
        s2[0][0] + s2[0][1] + s2[0][2] + s2[0][3],
        s2[1][0] + s2[1][1] + s2[1][2] + s2[1][3],
        s2[2][0] + s2[2][1] + s2[2][2] + s2[2][3] };
    const float TW = s2[3][0] + s2[3][1] + s2[3][2] + s2[3][3];
    const float NA = s2[4][0] + s2[4][1] + s2[4][2] + s2[4][3];
    const bool changed = (NA >= 1.5f);               // n_active >= 2

    f32x4* g4 = (f32x4*)gains;
    #pragma unroll
    for (int j = 0; j < 4; ++j) {
        const int vv = 4 * tid + j;
        const bool  act   = (sv[4][j] > 0.5f);
        const float w     = sv[3][j];               // cw*af == cw for active
        const float share = (w / fmaxf(TW, 1e-6f)) * ENERGY_THRESHOLD;
        const float ea[3] = { sv[0][j], sv[1][j], sv[2][j] };

        const float tbefore = ea[0] + ea[1] + ea[2];
        float tafter = 0.f;
        float g[3];
        #pragma unroll
        for (int b = 0; b < 3; ++b) {
            const float excess = ea[b] - share;
            const float exr    = excess / fmaxf(ea[b], 1e-6f);
            const float red    = fmaxf(0.3f, 1.0f - wd[vv * 3 + b] * exr * 0.5f);
            const bool apply   = (TE[b] > ENERGY_THRESHOLD) && (ea[b] > 0.0f) &&
                                 (excess > 0.0f) && act;
            const float gb = apply ? red : 1.0f;
            tafter += gb * ea[b];
            g[b] = changed ? gb : 1.0f;
        }
        const float nscale = (tbefore > 1e-6f) ? (tafter / tbefore) : 1.0f;
        f32x4 gv;
        gv[0] = g[0]; gv[1] = g[1]; gv[2] = g[2];
        gv[3] = (changed && act) ? nscale : 1.0f;
        g4[vv] = gv;
    }
}

// ---------------------------------------------------------------------------
// Kernel 2: elementwise apply with a featherweight preamble.
// Grid = V*8 blocks x 256. Block bid: v = bid>>3, part = bid&7.
// Parts 0-3 = harm quarter-rows, 4-7 = noise. 4 f32x4 per thread.
// NT stores only (out never re-read); caching loads keep inputs L3-warm.
// ---------------------------------------------------------------------------
__global__ __launch_bounds__(256)
void k2_apply(const float* __restrict__ harm,
              const float* __restrict__ noise,
              const float* __restrict__ f0_hz,
              const float* __restrict__ gains,
              float* __restrict__ out) {
    const int bid  = blockIdx.x;
    const int v    = bid >> 3;
    const int part = bid & 7;
    const int tid  = threadIdx.x;

    const f32x4 gv = ((const f32x4*)gains)[v];   // block-uniform
    f32x4* orow = (f32x4*)out + (size_t)v * 8192;

    if (part < 4) {
        const float f0 = f0_hz[v];
        const float g0 = gv[0], g1 = gv[1], g2 = gv[2];
        const f32x4* hrow = (const f32x4*)harm + (size_t)v * 4096;
        const int c0 = part * 1024 + tid;
        #pragma unroll
        for (int k = 0; k < 4; ++k) {
            const int c = c0 + k * 256;
            const f32x4 a = hrow[c];
            f32x4 o;
            #pragma unroll
            for (int j = 0; j < 4; ++j) {
                const float freq = f0 * (float)(c * 4 + j + 1);
                const float gg = (freq < BAND_LOW_MAX) ? g0
                               : (freq < BAND_MID_MAX) ? g1 : g2;
                o[j] = a[j] * gg;
            }
            __builtin_nontemporal_store(o, orow + c);
        }
    } else {
        const float nse = gv[3];
        const f32x4* nrow = (const f32x4*)noise + (size_t)v * 4096;
        const int c0 = (part - 4) * 1024 + tid;
        #pragma unroll
        for (int k = 0; k < 4; ++k) {
            const int c = c0 + k * 256;
            const f32x4 n = nrow[c];
            __builtin_nontemporal_store(n * nse, orow + 4096 + c);
        }
    }
}

// ---------------------------------------------------------------------------
extern "C" void kernel_launch(void* const* d_in, const int* in_sizes, int n_in,
                              void* d_out, int out_size, void* d_ws, size_t ws_size,
                              hipStream_t stream) {
    const float* harm  = (const float*)d_in[0];
    const float* noise = (const float*)d_in[1];
    const float* f0    = (const float*)d_in[2];
    const float* cw    = (const float*)d_in[3];
    const float* wd    = (const float*)d_in[4];
    const int*   act   = (const int*)d_in[5];
    float* out = (float*)d_out;

    float* stats = (float*)d_ws;                 // 5*V floats (20 KiB)
    float* gains = stats + 5 * V;                // V*4 floats (16 KiB)
    unsigned int* counter = (unsigned int*)(gains + 4 * V);

    // zero the arrival counter each call (graph-capture-safe memset node)
    hipMemsetAsync(counter, 0, sizeof(unsigned int), stream);

    k1_stats<<<V, 256, 0, stream>>>(harm, f0, cw, wd, act, stats, gains, counter);
    k2_apply<<<V * 8, 256, 0, stream>>>(harm, noise, f0, gains, out);
}

// Round 8
// 56.439 us; speedup vs baseline: 1.7761x; 1.7761x over previous
//
#include <hip/hip_runtime.h>

#define V   1024
#define NH  16384
#define NM  16384

#define BAND_LOW_MAX    500.0f
#define BAND_MID_MAX    2000.0f
#define ENERGY_THRESHOLD 0.5f

// clang native vector type (required by __builtin_nontemporal_*)
typedef float f32x4 __attribute__((ext_vector_type(4)));

// ---------------------------------------------------------------------------
// Kernel 1: per-voice band stats. One block per voice.
// stats planar [5][V]: {E_low*af, E_mid*af, E_high*af, cw*af, af}
// Regular caching loads: harm should stay L3-resident for kernel 2's re-read.
// ---------------------------------------------------------------------------
__global__ __launch_bounds__(256)
void k1_stats(const float* __restrict__ harm,
              const float* __restrict__ f0_hz,
              const float* __restrict__ cw,
              const int*   __restrict__ is_active,
              float* __restrict__ stats /* [5][V] */) {
    const int v   = blockIdx.x;
    const int tid = threadIdx.x;
    const float f0 = f0_hz[v];
    const f32x4* hrow = (const f32x4*)harm + (size_t)v * 4096;

    float e0 = 0.f, e1 = 0.f, e2 = 0.f;
    #pragma unroll
    for (int k = 0; k < 16; ++k) {
        const f32x4 a = hrow[tid + k * 256];
        const int hbase = (tid + k * 256) * 4;
        #pragma unroll
        for (int j = 0; j < 4; ++j) {
            const float freq = f0 * (float)(hbase + j + 1);  // fp32 mul, matches jnp
            if (freq < BAND_LOW_MAX)       e0 += a[j];
            else if (freq < BAND_MID_MAX)  e1 += a[j];
            else                           e2 += a[j];
        }
    }
    for (int off = 32; off > 0; off >>= 1) {
        e0 += __shfl_down(e0, off);
        e1 += __shfl_down(e1, off);
        e2 += __shfl_down(e2, off);
    }
    __shared__ float s[3][4];
    const int wid  = tid >> 6;
    const int lane = tid & 63;
    if (lane == 0) { s[0][wid] = e0; s[1][wid] = e1; s[2][wid] = e2; }
    __syncthreads();
    if (tid == 0) {
        const float t0 = s[0][0] + s[0][1] + s[0][2] + s[0][3];
        const float t1 = s[1][0] + s[1][1] + s[1][2] + s[1][3];
        const float t2 = s[2][0] + s[2][1] + s[2][2] + s[2][3];
        const float af = (is_active[v] != 0) ? 1.0f : 0.0f;
        stats[0 * V + v] = t0 * af;
        stats[1 * V + v] = t1 * af;
        stats[2 * V + v] = t2 * af;
        stats[3 * V + v] = cw[v] * af;
        stats[4 * V + v] = af;
    }
}

// ---------------------------------------------------------------------------
// Kernel 2: fused totals-reduce + gains + elementwise apply.
// Grid = V*8 blocks of 256; v = bid>>3, part = bid&7.
// ISSUE-EARLY: the 4 streaming f32x4 loads are issued FIRST (registers),
// then the stats reduce + gain math runs while they're in flight (~900 cyc
// HBM latency covers the ~500-1000 cyc preamble), then multiply + NT-store.
// ---------------------------------------------------------------------------
__global__ __launch_bounds__(256)
void k2_apply(const float* __restrict__ harm,
              const float* __restrict__ noise,
              const float* __restrict__ f0_hz,
              const float* __restrict__ cw,
              const float* __restrict__ wd,
              const int*   __restrict__ is_active,
              const float* __restrict__ stats,
              float* __restrict__ out) {
    const int bid  = blockIdx.x;
    const int v    = bid >> 3;
    const int part = bid & 7;
    const int tid  = threadIdx.x;

    // ---- issue streaming loads FIRST (no dependence on the preamble) -----
    const bool is_harm = (part < 4);
    const int  c0 = (is_harm ? part * 1024 : (part - 4) * 1024) + tid;
    const f32x4* srow = is_harm ? ((const f32x4*)harm  + (size_t)v * 4096)
                                : ((const f32x4*)noise + (size_t)v * 4096);
    f32x4 d0 = srow[c0];
    f32x4 d1 = srow[c0 + 256];
    f32x4 d2 = srow[c0 + 512];
    f32x4 d3 = srow[c0 + 768];

    // ---- preamble: totals over stats (runs while loads are in flight) ----
    const f32x4* sp = (const f32x4*)stats;
    const f32x4 x0 = sp[0 * 256 + tid];
    const f32x4 x1 = sp[1 * 256 + tid];
    const f32x4 x2 = sp[2 * 256 + tid];
    const f32x4 x3 = sp[3 * 256 + tid];
    const f32x4 x4 = sp[4 * 256 + tid];
    float r0 = (x0[0] + x0[1]) + (x0[2] + x0[3]);
    float r1 = (x1[0] + x1[1]) + (x1[2] + x1[3]);
    float r2 = (x2[0] + x2[1]) + (x2[2] + x2[3]);
    float r3 = (x3[0] + x3[1]) + (x3[2] + x3[3]);
    float r4 = (x4[0] + x4[1]) + (x4[2] + x4[3]);
    for (int off = 32; off > 0; off >>= 1) {
        r0 += __shfl_down(r0, off);
        r1 += __shfl_down(r1, off);
        r2 += __shfl_down(r2, off);
        r3 += __shfl_down(r3, off);
        r4 += __shfl_down(r4, off);
    }
    __shared__ float s2[5][4];
    const int wid  = tid >> 6;
    const int lane = tid & 63;
    if (lane == 0) {
        s2[0][wid] = r0; s2[1][wid] = r1; s2[2][wid] = r2;
        s2[3][wid] = r3; s2[4][wid] = r4;
    }
    __syncthreads();
    const float TE[3] = {
        s2[0][0] + s2[0][1] + s2[0][2] + s2[0][3],
        s2[1][0] + s2[1][1] + s2[1][2] + s2[1][3],
        s2[2][0] + s2[2][1] + s2[2][2] + s2[2][3] };
    const float TW = s2[3][0] + s2[3][1] + s2[3][2] + s2[3][3];
    const float NA = s2[4][0] + s2[4][1] + s2[4][2] + s2[4][3];
    const bool changed = (NA >= 1.5f);               // n_active >= 2

    // ---- per-voice gains (block-uniform scalar loads) ---------------------
    const bool  act   = (is_active[v] != 0);
    const float w     = cw[v];
    const float share = (w / fmaxf(TW, 1e-6f)) * ENERGY_THRESHOLD;
    const float ea[3] = { stats[0 * V + v], stats[1 * V + v], stats[2 * V + v] };

    const float tbefore = ea[0] + ea[1] + ea[2];
    float tafter = 0.f;
    float g[3];
    #pragma unroll
    for (int b = 0; b < 3; ++b) {
        const float excess = ea[b] - share;
        const float exr    = excess / fmaxf(ea[b], 1e-6f);
        const float red    = fmaxf(0.3f, 1.0f - wd[v * 3 + b] * exr * 0.5f);
        const bool apply   = (TE[b] > ENERGY_THRESHOLD) && (ea[b] > 0.0f) &&
                             (excess > 0.0f) && act;
        const float gb = apply ? red : 1.0f;
        tafter += gb * ea[b];
        g[b] = changed ? gb : 1.0f;
    }
    const float nscale = (tbefore > 1e-6f) ? (tafter / tbefore) : 1.0f;
    const float nse    = (changed && act) ? nscale : 1.0f;
    const float g0 = g[0], g1 = g[1], g2 = g[2];

    // ---- consume: multiply + NT store -------------------------------------
    f32x4* orow = (f32x4*)out + (size_t)v * 8192;
    if (is_harm) {
        const float f0 = f0_hz[v];
        f32x4 dat[4] = { d0, d1, d2, d3 };
        #pragma unroll
        for (int k = 0; k < 4; ++k) {
            const int c = c0 + k * 256;
            f32x4 o;
            #pragma unroll
            for (int j = 0; j < 4; ++j) {
                const float freq = f0 * (float)(c * 4 + j + 1);
                const float gg = (freq < BAND_LOW_MAX) ? g0
                               : (freq < BAND_MID_MAX) ? g1 : g2;
                o[j] = dat[k][j] * gg;
            }
            __builtin_nontemporal_store(o, orow + c);
        }
    } else {
        __builtin_nontemporal_store(d0 * nse, orow + 4096 + c0);
        __builtin_nontemporal_store(d1 * nse, orow + 4096 + c0 + 256);
        __builtin_nontemporal_store(d2 * nse, orow + 4096 + c0 + 512);
        __builtin_nontemporal_store(d3 * nse, orow + 4096 + c0 + 768);
    }
}

// ---------------------------------------------------------------------------
extern "C" void kernel_launch(void* const* d_in, const int* in_sizes, int n_in,
                              void* d_out, int out_size, void* d_ws, size_t ws_size,
                              hipStream_t stream) {
    const float* harm  = (const float*)d_in[0];
    const float* noise = (const float*)d_in[1];
    const float* f0    = (const float*)d_in[2];
    const float* cw    = (const float*)d_in[3];
    const float* wd    = (const float*)d_in[4];
    const int*   act   = (const int*)d_in[5];
    float* out   = (float*)d_out;
    float* stats = (float*)d_ws;   // 5*V floats

    k1_stats<<<V, 256, 0, stream>>>(harm, f0, cw, act, stats);
    k2_apply<<<V * 8, 256, 0, stream>>>(harm, noise, f0, cw, wd, act, stats, out);
}

// Round 9
// 55.370 us; speedup vs baseline: 1.8104x; 1.0193x over previous
//
#include <hip/hip_runtime.h>

#define V   1024
#define NH  16384
#define NM  16384

#define BAND_LOW_MAX    500.0f
#define BAND_MID_MAX    2000.0f
#define ENERGY_THRESHOLD 0.5f

// clang native vector type (required by __builtin_nontemporal_*)
typedef float f32x4 __attribute__((ext_vector_type(4)));

// ---------------------------------------------------------------------------
// Kernel 1: per-voice band stats, TWO blocks per voice (32 waves/CU).
// Block b: v = b>>1, half = b&1; covers 2048 harmonics (8 f32x4/thread).
// pstats planar [5][2V], slot = 2v+half:
//   planes 0-2: partial E_b*af ; planes 3,4 (cw*af, af): half0 only, half1=0.
// Regular caching loads: harm must stay L3-resident for kernel 2's re-read.
// ---------------------------------------------------------------------------
__global__ __launch_bounds__(256)
void k1_stats(const float* __restrict__ harm,
              const float* __restrict__ f0_hz,
              const float* __restrict__ cw,
              const int*   __restrict__ is_active,
              float* __restrict__ pstats /* [5][2V] */) {
    const int b    = blockIdx.x;
    const int v    = b >> 1;
    const int half = b & 1;
    const int tid  = threadIdx.x;
    const float f0 = f0_hz[v];
    const f32x4* hrow = (const f32x4*)harm + (size_t)v * 4096 + half * 2048;

    float e0 = 0.f, e1 = 0.f, e2 = 0.f;
    #pragma unroll
    for (int k = 0; k < 8; ++k) {
        const f32x4 a = hrow[tid + k * 256];
        const int hbase = (half * 2048 + tid + k * 256) * 4;
        #pragma unroll
        for (int j = 0; j < 4; ++j) {
            const float freq = f0 * (float)(hbase + j + 1);  // fp32 mul, matches jnp
            if (freq < BAND_LOW_MAX)       e0 += a[j];
            else if (freq < BAND_MID_MAX)  e1 += a[j];
            else                           e2 += a[j];
        }
    }
    for (int off = 32; off > 0; off >>= 1) {
        e0 += __shfl_down(e0, off);
        e1 += __shfl_down(e1, off);
        e2 += __shfl_down(e2, off);
    }
    __shared__ float s[3][4];
    const int wid  = tid >> 6;
    const int lane = tid & 63;
    if (lane == 0) { s[0][wid] = e0; s[1][wid] = e1; s[2][wid] = e2; }
    __syncthreads();
    if (tid == 0) {
        const float t0 = s[0][0] + s[0][1] + s[0][2] + s[0][3];
        const float t1 = s[1][0] + s[1][1] + s[1][2] + s[1][3];
        const float t2 = s[2][0] + s[2][1] + s[2][2] + s[2][3];
        const float af = (is_active[v] != 0) ? 1.0f : 0.0f;
        const int slot = 2 * v + half;
        pstats[0 * 2048 + slot] = t0 * af;
        pstats[1 * 2048 + slot] = t1 * af;
        pstats[2 * 2048 + slot] = t2 * af;
        pstats[3 * 2048 + slot] = half ? 0.0f : cw[v] * af;
        pstats[4 * 2048 + slot] = half ? 0.0f : af;
    }
}

// ---------------------------------------------------------------------------
// Kernel 2: fused totals-reduce + gains + elementwise apply.
// Grid = V*8 blocks of 256; v = bid>>3, part = bid&7.
// ISSUE-EARLY: streaming loads first; preamble runs while in flight.
// Noise loads are NONTEMPORAL (read-once -> evict-first, protects harm's
// L3 residency). Out stores NT. Harm loads caching.
// ---------------------------------------------------------------------------
__global__ __launch_bounds__(256)
void k2_apply(const float* __restrict__ harm,
              const float* __restrict__ noise,
              const float* __restrict__ f0_hz,
              const float* __restrict__ cw,
              const float* __restrict__ wd,
              const int*   __restrict__ is_active,
              const float* __restrict__ pstats,
              float* __restrict__ out) {
    const int bid  = blockIdx.x;
    const int v    = bid >> 3;
    const int part = bid & 7;
    const int tid  = threadIdx.x;

    // ---- issue streaming loads FIRST (no dependence on the preamble) -----
    const bool is_harm = (part < 4);
    const int  c0 = (is_harm ? part * 1024 : (part - 4) * 1024) + tid;
    f32x4 d0, d1, d2, d3;
    if (is_harm) {
        const f32x4* srow = (const f32x4*)harm + (size_t)v * 4096;
        d0 = srow[c0];
        d1 = srow[c0 + 256];
        d2 = srow[c0 + 512];
        d3 = srow[c0 + 768];
    } else {
        const f32x4* srow = (const f32x4*)noise + (size_t)v * 4096;
        d0 = __builtin_nontemporal_load(srow + c0);
        d1 = __builtin_nontemporal_load(srow + c0 + 256);
        d2 = __builtin_nontemporal_load(srow + c0 + 512);
        d3 = __builtin_nontemporal_load(srow + c0 + 768);
    }

    // ---- preamble: totals over pstats [5][2048] (hidden under loads) -----
    const f32x4* sp = (const f32x4*)pstats;   // plane p = 512 f32x4
    float r[5];
    #pragma unroll
    for (int p = 0; p < 5; ++p) {
        const f32x4 xa = sp[p * 512 + tid];
        const f32x4 xb = sp[p * 512 + 256 + tid];
        r[p] = ((xa[0] + xa[1]) + (xa[2] + xa[3]))
             + ((xb[0] + xb[1]) + (xb[2] + xb[3]));
    }
    #pragma unroll
    for (int p = 0; p < 5; ++p)
        for (int off = 32; off > 0; off >>= 1)
            r[p] += __shfl_down(r[p], off);
    __shared__ float s2[5][4];
    const int wid  = tid >> 6;
    const int lane = tid & 63;
    if (lane == 0) {
        #pragma unroll
        for (int p = 0; p < 5; ++p) s2[p][wid] = r[p];
    }
    __syncthreads();
    const float TE[3] = {
        s2[0][0] + s2[0][1] + s2[0][2] + s2[0][3],
        s2[1][0] + s2[1][1] + s2[1][2] + s2[1][3],
        s2[2][0] + s2[2][1] + s2[2][2] + s2[2][3] };
    const float TW = s2[3][0] + s2[3][1] + s2[3][2] + s2[3][3];
    const float NA = s2[4][0] + s2[4][1] + s2[4][2] + s2[4][3];
    const bool changed = (NA >= 1.5f);               // n_active >= 2

    // ---- per-voice gains (block-uniform scalar loads) ---------------------
    const bool  act   = (is_active[v] != 0);
    const float w     = cw[v];
    const float share = (w / fmaxf(TW, 1e-6f)) * ENERGY_THRESHOLD;
    const float ea[3] = {
        pstats[0 * 2048 + 2 * v] + pstats[0 * 2048 + 2 * v + 1],
        pstats[1 * 2048 + 2 * v] + pstats[1 * 2048 + 2 * v + 1],
        pstats[2 * 2048 + 2 * v] + pstats[2 * 2048 + 2 * v + 1] };

    const float tbefore = ea[0] + ea[1] + ea[2];
    float tafter = 0.f;
    float g[3];
    #pragma unroll
    for (int b = 0; b < 3; ++b) {
        const float excess = ea[b] - share;
        const float exr    = excess / fmaxf(ea[b], 1e-6f);
        const float red    = fmaxf(0.3f, 1.0f - wd[v * 3 + b] * exr * 0.5f);
        const bool apply   = (TE[b] > ENERGY_THRESHOLD) && (ea[b] > 0.0f) &&
                             (excess > 0.0f) && act;
        const float gb = apply ? red : 1.0f;
        tafter += gb * ea[b];
        g[b] = changed ? gb : 1.0f;
    }
    const float nscale = (tbefore > 1e-6f) ? (tafter / tbefore) : 1.0f;
    const float nse    = (changed && act) ? nscale : 1.0f;
    const float g0 = g[0], g1 = g[1], g2 = g[2];

    // ---- consume: multiply + NT store -------------------------------------
    f32x4* orow = (f32x4*)out + (size_t)v * 8192;
    if (is_harm) {
        const float f0 = f0_hz[v];
        f32x4 dat[4] = { d0, d1, d2, d3 };
        #pragma unroll
        for (int k = 0; k < 4; ++k) {
            const int c = c0 + k * 256;
            f32x4 o;
            #pragma unroll
            for (int j = 0; j < 4; ++j) {
                const float freq = f0 * (float)(c * 4 + j + 1);
                const float gg = (freq < BAND_LOW_MAX) ? g0
                               : (freq < BAND_MID_MAX) ? g1 : g2;
                o[j] = dat[k][j] * gg;
            }
            __builtin_nontemporal_store(o, orow + c);
        }
    } else {
        __builtin_nontemporal_store(d0 * nse, orow + 4096 + c0);
        __builtin_nontemporal_store(d1 * nse, orow + 4096 + c0 + 256);
        __builtin_nontemporal_store(d2 * nse, orow + 4096 + c0 + 512);
        __builtin_nontemporal_store(d3 * nse, orow + 4096 + c0 + 768);
    }
}

// ---------------------------------------------------------------------------
extern "C" void kernel_launch(void* const* d_in, const int* in_sizes, int n_in,
                              void* d_out, int out_size, void* d_ws, size_t ws_size,
                              hipStream_t stream) {
    const float* harm  = (const float*)d_in[0];
    const float* noise = (const float*)d_in[1];
    const float* f0    = (const float*)d_in[2];
    const float* cw    = (const float*)d_in[3];
    const float* wd    = (const float*)d_in[4];
    const int*   act   = (const int*)d_in[5];
    float* out    = (float*)d_out;
    float* pstats = (float*)d_ws;   // 5*2048 floats (40 KiB)

    k1_stats<<<2 * V, 256, 0, stream>>>(harm, f0, cw, act, pstats);
    k2_apply<<<V * 8, 256, 0, stream>>>(harm, noise, f0, cw, wd, act, pstats, out);
}